// Round 1
// baseline (9700.872 us; speedup 1.0000x reference)
//
#include <hip/hip_runtime.h>
#include <hip/hip_bf16.h>
#include <math.h>

#define DEPTH 24
#define D_MODEL 192
#define D_INNER 384
#define D_STATE 16
#define DT_RANK 12
#define NCLS 1000
#define PATCHSZ 16
#define IMG 224
#define GSZ 14
#define L_TOK 196
#define BATCH 64
#define M_ROWS (BATCH*L_TOK)   // 12544
#define EPSV 1e-5f

// ---------------------------------------------------------------- utilities
__device__ __forceinline__ float silu_(float x) {
    return x / (1.f + __expf(-x));
}

// ---------------------------------------------------------------- im2col for patch embedding
__global__ __launch_bounds__(256) void im2col_k(const float* __restrict__ x,
                                                float* __restrict__ Acol) {
    int idx = blockIdx.x * 256 + threadIdx.x;
    if (idx >= M_ROWS * 768) return;
    int row = idx / 768, k = idx % 768;
    int b = row / L_TOK, l = row % L_TOK;
    int i = l / GSZ, j = l % GSZ;
    int c = k >> 8, r = k & 255, p = r >> 4, q = r & 15;
    Acol[idx] = x[((size_t)(b * 3 + c) * IMG + (i * PATCHSZ + p)) * IMG + (j * PATCHSZ + q)];
}

// ---------------------------------------------------------------- generic fp32 GEMM:  C[M,N] = A[M,K] * B[N,K]^T  (+bias, +softplus)
// act: 0 = none, 1 = +bias, 2 = +bias then softplus
__global__ __launch_bounds__(256) void gemm_nt(
    const float* __restrict__ A, int lda,
    const float* __restrict__ B, int ldb,
    float* __restrict__ C, int ldc,
    int M, int N, int K,
    const float* __restrict__ bias, int act)
{
    __shared__ float As[16][68];
    __shared__ float Bs[16][68];
    const int t = threadIdx.x;
    const int tx = t & 15, ty = t >> 4;
    const int bm = blockIdx.y * 64, bn = blockIdx.x * 64;
    float acc[4][4] = {};
    const int kk = t & 15, m0 = t >> 4;

    for (int k0 = 0; k0 < K; k0 += 16) {
        int gk = k0 + kk;
        bool kok = gk < K;
#pragma unroll
        for (int p = 0; p < 4; ++p) {
            int mm = m0 + p * 16;
            int gm = bm + mm;
            As[kk][mm] = (kok && gm < M) ? A[(size_t)gm * lda + gk] : 0.f;
            int gn = bn + mm;
            Bs[kk][mm] = (kok && gn < N) ? B[(size_t)gn * ldb + gk] : 0.f;
        }
        __syncthreads();
#pragma unroll
        for (int k = 0; k < 16; ++k) {
            float4 av = *(const float4*)&As[k][ty * 4];
            float4 bv = *(const float4*)&Bs[k][tx * 4];
            float a0 = av.x, a1 = av.y, a2 = av.z, a3 = av.w;
            float b0 = bv.x, b1 = bv.y, b2 = bv.z, b3 = bv.w;
            acc[0][0] += a0 * b0; acc[0][1] += a0 * b1; acc[0][2] += a0 * b2; acc[0][3] += a0 * b3;
            acc[1][0] += a1 * b0; acc[1][1] += a1 * b1; acc[1][2] += a1 * b2; acc[1][3] += a1 * b3;
            acc[2][0] += a2 * b0; acc[2][1] += a2 * b1; acc[2][2] += a2 * b2; acc[2][3] += a2 * b3;
            acc[3][0] += a3 * b0; acc[3][1] += a3 * b1; acc[3][2] += a3 * b2; acc[3][3] += a3 * b3;
        }
        __syncthreads();
    }
#pragma unroll
    for (int i2 = 0; i2 < 4; ++i2) {
        int gm = bm + ty * 4 + i2;
        if (gm >= M) continue;
#pragma unroll
        for (int j = 0; j < 4; ++j) {
            int gn = bn + tx * 4 + j;
            if (gn >= N) continue;
            float v = acc[i2][j];
            if (act >= 1 && bias) v += bias[gn];
            if (act == 2) v = (v > 20.f) ? v : log1pf(__expf(v));
            C[(size_t)gm * ldc + gn] = v;
        }
    }
}

// ---------------------------------------------------------------- fused residual add + LayerNorm
// add==0: resid = hid;  add==1: resid += hid;  then hn = LN(resid)*w + b
__global__ __launch_bounds__(256) void ln_resid_k(
    const float* __restrict__ hid, float* __restrict__ resid,
    float* __restrict__ hn, const float* __restrict__ w,
    const float* __restrict__ b, int add)
{
    int wave = threadIdx.x >> 6, lane = threadIdx.x & 63;
    int row = blockIdx.x * 4 + wave;
    if (row >= M_ROWS) return;
    const float* hr = hid + (size_t)row * D_MODEL;
    float* rr = resid + (size_t)row * D_MODEL;
    float v[3];
#pragma unroll
    for (int j = 0; j < 3; ++j) {
        int e = lane + 64 * j;
        float h = hr[e];
        if (add) h += rr[e];
        rr[e] = h;
        v[j] = h;
    }
    float s = v[0] + v[1] + v[2];
    float sq = v[0] * v[0] + v[1] * v[1] + v[2] * v[2];
#pragma unroll
    for (int m = 1; m < 64; m <<= 1) {
        s += __shfl_xor(s, m, 64);
        sq += __shfl_xor(sq, m, 64);
    }
    float mu = s * (1.f / 192.f);
    float var = sq * (1.f / 192.f) - mu * mu;
    float ve = var + EPSV;
    float rs = rsqrtf(ve);
    rs = rs * (1.5f - 0.5f * ve * rs * rs);   // Newton refine
    float* hnr = hn + (size_t)row * D_MODEL;
#pragma unroll
    for (int j = 0; j < 3; ++j) {
        int e = lane + 64 * j;
        hnr[e] = (v[j] - mu) * rs * w[e] + b[e];
    }
}

// ---------------------------------------------------------------- depthwise causal conv (k=4) + SiLU
__global__ __launch_bounds__(256) void conv_silu_k(
    const float* __restrict__ xz, const float* __restrict__ cw,
    const float* __restrict__ cb, float* __restrict__ xc)
{
    int idx = blockIdx.x * 256 + threadIdx.x;
    if (idx >= M_ROWS * D_INNER) return;
    int d = idx % D_INNER;
    int row = idx / D_INNER;
    int l = row % L_TOK;
    float acc = cb[d];
    const float* cwd = cw + d * 4;
#pragma unroll
    for (int k = 0; k < 4; ++k) {
        int ls = l + k - 3;
        if (ls >= 0) acc += xz[(size_t)(row + k - 3) * 768 + d] * cwd[k];
    }
    xc[idx] = silu_(acc);
}

// ---------------------------------------------------------------- selective scan (16 lanes per (b,d) channel: one per state n)
__global__ __launch_bounds__(256) void scan_k(
    const float* __restrict__ delta, const float* __restrict__ xc,
    const float* __restrict__ dbc, const float* __restrict__ xz,
    const float* __restrict__ A_log, const float* __restrict__ Dp,
    float* __restrict__ y)
{
    int t = threadIdx.x;
    int n = t & 15, sub = (t >> 4) & 3, wave = t >> 6;
    int ch = blockIdx.x * 16 + wave * 4 + sub;       // ch = b*384 + d, < 24576
    int b = ch / D_INNER, d = ch % D_INNER;
    float A = -__expf(A_log[d * D_STATE + n]);
    float Dv = Dp[d];
    float h = 0.f;
    size_t rowbase = (size_t)b * L_TOK;
    for (int l = 0; l < L_TOK; ++l) {
        size_t row = rowbase + l;
        float dl = delta[row * D_INNER + d];
        float xcv = xc[row * D_INNER + d];
        float Bn = dbc[row * 44 + DT_RANK + n];
        float Cn = dbc[row * 44 + DT_RANK + D_STATE + n];
        h = __expf(dl * A) * h + (dl * xcv) * Bn;
        float p = h * Cn;
        p += __shfl_xor(p, 1, 64);
        p += __shfl_xor(p, 2, 64);
        p += __shfl_xor(p, 4, 64);
        p += __shfl_xor(p, 8, 64);
        if (n == 0) {
            float z = xz[row * 768 + D_INNER + d];
            y[row * D_INNER + d] = (p + Dv * xcv) * silu_(z);
        }
    }
}

// ---------------------------------------------------------------- final LN on last token only
__global__ __launch_bounds__(64) void final_ln_k(
    const float* __restrict__ hid, const float* __restrict__ w,
    const float* __restrict__ b, float* __restrict__ feat)
{
    int bb = blockIdx.x;
    int lane = threadIdx.x;
    const float* hr = hid + ((size_t)bb * L_TOK + (L_TOK - 1)) * D_MODEL;
    float v[3];
#pragma unroll
    for (int j = 0; j < 3; ++j) v[j] = hr[lane + 64 * j];
    float s = v[0] + v[1] + v[2];
    float sq = v[0] * v[0] + v[1] * v[1] + v[2] * v[2];
#pragma unroll
    for (int m = 1; m < 64; m <<= 1) {
        s += __shfl_xor(s, m, 64);
        sq += __shfl_xor(sq, m, 64);
    }
    float mu = s * (1.f / 192.f);
    float var = sq * (1.f / 192.f) - mu * mu;
    float ve = var + EPSV;
    float rs = rsqrtf(ve);
    rs = rs * (1.5f - 0.5f * ve * rs * rs);
#pragma unroll
    for (int j = 0; j < 3; ++j) {
        int e = lane + 64 * j;
        feat[(size_t)bb * D_MODEL + e] = (v[j] - mu) * rs * w[e] + b[e];
    }
}

// ================================================================ host
extern "C" void kernel_launch(void* const* d_in, const int* in_sizes, int n_in,
                              void* d_out, int out_size, void* d_ws, size_t ws_size,
                              hipStream_t stream) {
    const float* x         = (const float*)d_in[0];
    const float* patch_w   = (const float*)d_in[1];
    const float* patch_b   = (const float*)d_in[2];
    const float* norm_w    = (const float*)d_in[3];
    const float* norm_b    = (const float*)d_in[4];
    const float* in_proj_w = (const float*)d_in[5];
    const float* conv_w    = (const float*)d_in[6];
    const float* conv_b    = (const float*)d_in[7];
    const float* x_proj_w  = (const float*)d_in[8];
    const float* dt_proj_w = (const float*)d_in[9];
    const float* dt_proj_b = (const float*)d_in[10];
    const float* A_log     = (const float*)d_in[11];
    const float* Dp        = (const float*)d_in[12];
    const float* out_proj_w= (const float*)d_in[13];
    const float* normf_w   = (const float*)d_in[14];
    const float* normf_b   = (const float*)d_in[15];
    const float* head_w    = (const float*)d_in[16];
    const float* head_b    = (const float*)d_in[17];
    float* out = (float*)d_out;

    // workspace layout (floats)
    float* ws    = (float*)d_ws;
    float* resid = ws;                       // 12544*192
    float* hid   = resid + (size_t)M_ROWS * D_MODEL;
    float* hn    = hid   + (size_t)M_ROWS * D_MODEL;
    float* xz    = hn    + (size_t)M_ROWS * D_MODEL;   // 12544*768, also im2col buffer
    float* xc    = xz    + (size_t)M_ROWS * 768;       // 12544*384
    float* dbc   = xc    + (size_t)M_ROWS * D_INNER;   // 12544*44
    float* delta = dbc   + (size_t)M_ROWS * 44;        // 12544*384
    float* ybuf  = delta + (size_t)M_ROWS * D_INNER;   // 12544*384
    float* feat  = ybuf  + (size_t)M_ROWS * D_INNER;   // 64*192

    // ---- patch embedding: im2col + GEMM -> hid
    im2col_k<<<(M_ROWS * 768) / 256, 256, 0, stream>>>(x, xz);
    {
        dim3 g((D_MODEL + 63) / 64, M_ROWS / 64);
        gemm_nt<<<g, 256, 0, stream>>>(xz, 768, patch_w, 768, hid, D_MODEL,
                                       M_ROWS, D_MODEL, 768, patch_b, 1);
    }

    // ---- 24 mamba layers
    for (int i = 0; i < DEPTH; ++i) {
        const float* nw  = norm_w    + (size_t)i * D_MODEL;
        const float* nb  = norm_b    + (size_t)i * D_MODEL;
        const float* iw  = in_proj_w + (size_t)i * 768 * D_MODEL;
        const float* cwp = conv_w    + (size_t)i * D_INNER * 4;
        const float* cbp = conv_b    + (size_t)i * D_INNER;
        const float* xw  = x_proj_w  + (size_t)i * 44 * D_INNER;
        const float* dtw = dt_proj_w + (size_t)i * D_INNER * DT_RANK;
        const float* dtb = dt_proj_b + (size_t)i * D_INNER;
        const float* al  = A_log     + (size_t)i * D_INNER * D_STATE;
        const float* dp  = Dp        + (size_t)i * D_INNER;
        const float* ow  = out_proj_w+ (size_t)i * D_MODEL * D_INNER;

        // residual + LN
        ln_resid_k<<<M_ROWS / 4, 256, 0, stream>>>(hid, resid, hn, nw, nb, i > 0 ? 1 : 0);

        // in_proj: xz[M,768] = hn @ iw^T
        {
            dim3 g(768 / 64, M_ROWS / 64);
            gemm_nt<<<g, 256, 0, stream>>>(hn, D_MODEL, iw, D_MODEL, xz, 768,
                                           M_ROWS, 768, D_MODEL, nullptr, 0);
        }
        // conv + silu -> xc
        conv_silu_k<<<(M_ROWS * D_INNER) / 256, 256, 0, stream>>>(xz, cwp, cbp, xc);
        // x_proj: dbc[M,44] = xc @ xw^T
        {
            dim3 g(1, M_ROWS / 64);
            gemm_nt<<<g, 256, 0, stream>>>(xc, D_INNER, xw, D_INNER, dbc, 44,
                                           M_ROWS, 44, D_INNER, nullptr, 0);
        }
        // dt_proj + softplus: delta[M,384] = softplus(dbc[:, :12] @ dtw^T + dtb)
        {
            dim3 g(D_INNER / 64, M_ROWS / 64);
            gemm_nt<<<g, 256, 0, stream>>>(dbc, 44, dtw, DT_RANK, delta, D_INNER,
                                           M_ROWS, D_INNER, DT_RANK, dtb, 2);
        }
        // selective scan -> ybuf (fused +D*xc and *silu(z))
        scan_k<<<(BATCH * D_INNER * 16) / 256, 256, 0, stream>>>(
            delta, xc, dbc, xz, al, dp, ybuf);
        // out_proj: hid[M,192] = ybuf @ ow^T
        {
            dim3 g(D_MODEL / 64, M_ROWS / 64);
            gemm_nt<<<g, 256, 0, stream>>>(ybuf, D_INNER, ow, D_INNER, hid, D_MODEL,
                                           M_ROWS, D_MODEL, D_INNER, nullptr, 0);
        }
    }

    // ---- final LN (last token only) + head
    final_ln_k<<<BATCH, 64, 0, stream>>>(hid, normf_w, normf_b, feat);
    {
        dim3 g((NCLS + 63) / 64, (BATCH + 63) / 64);
        gemm_nt<<<g, 256, 0, stream>>>(feat, D_MODEL, head_w, D_MODEL, out, NCLS,
                                       BATCH, NCLS, D_MODEL, head_b, 1);
    }
}